// Round 7
// baseline (48.972 us; speedup 1.0000x reference)
//
#include <hip/hip_runtime.h>

// Resample1d: out[b,c,h,w] = lerp of input1[b,c,h,:] at x = w + disp[b,h,w],
// zeroed where x outside [0, W-1].
// Shapes: input1 (B,C,H,W) f32, input2 (B,1,H,W) f32, out (B,C,H,W) f32.
//
// R7: back to R3's conflict-free tap mapping (w = lane + 64*p: LDS tap reads
// are stride-1 across lanes -> ~2 lanes/bank, free), which R3 measured at
// 0.79M conflict cycles vs 4.0-4.5M for the 4*lane+j mapping (R5/R6).
// Keep R5's MLP fixes: 2-deep prefetch ring, loads issued before params.
// New: tap pairs read as rb[a], rb[a+1] (one ds_read2_b32) — valid because
// whenever weights are nonzero i1 == i0+1; padded finite word at rb[512]
// covers the x==511 edge. Stores are scalar NT dwords (coalesced 256B/instr).

#define B 4
#define C 64
#define H 256
#define W 512
#define WAVES 4          // waves per block
#define CPW 8            // channels per wave
#define WPAD (W + 4)     // 516 floats = 2064B per wave chunk, keeps 16B align
// grid = (B*H, C/(WAVES*CPW)) = (1024, 2); block = 256

typedef float f32x4 __attribute__((ext_vector_type(4)));

__global__ __launch_bounds__(256) void resample1d_kernel(
    const float* __restrict__ in1,   // (B,C,H,W)
    const float* __restrict__ in2,   // (B,1,H,W)
    float* __restrict__ out)         // (B,C,H,W)
{
    __shared__ float rowbuf[WAVES][WPAD];   // wave-private chunks

    const int tid  = threadIdx.x;
    const int wid  = tid >> 6;
    const int lane = tid & 63;

    const int bh = blockIdx.x;          // 0..B*H-1
    const int b  = bh >> 8;             // / H  (H=256)
    const int cbase = blockIdx.y * (WAVES * CPW) + wid * CPW;

    const size_t chan_stride = (size_t)H * W;
    const float* src = in1 + ((size_t)b * C + cbase) * chan_stride + (size_t)(bh & (H - 1)) * W;
    float*       dst = out + ((size_t)b * C + cbase) * chan_stride + (size_t)(bh & (H - 1)) * W;
    const float* disp_row = in2 + (size_t)bh * W;

    // ---- issue first two channels' loads up front (2-deep ring) ----
    f32x4 pre0[2], pre1[2];
    pre0[0] = *(const f32x4*)(src + 4 * lane);
    pre1[0] = *(const f32x4*)(src + 256 + 4 * lane);
    pre0[1] = *(const f32x4*)(src + chan_stride + 4 * lane);
    pre1[1] = *(const f32x4*)(src + chan_stride + 256 + 4 * lane);

    // disp loads (coalesced 256B/instr), issued before param VALU work
    float dv[8];
    #pragma unroll
    for (int p = 0; p < 8; ++p) dv[p] = disp_row[lane + 64 * p];

    float* rb = rowbuf[wid];
    if (lane == 0) rb[W] = 0.0f;     // finite pad word for the i0==511 pair read

    // ---- per-lane pixel params, w = lane + 64*p (hoisted over channels) ----
    int   i0[8];
    float w0[8], w1[8];
    #pragma unroll
    for (int p = 0; p < 8; ++p) {
        int w = lane + 64 * p;
        float x = (float)w + dv[p];
        bool valid = (x >= 0.0f) && (x <= (float)(W - 1));
        float x0 = floorf(x);
        float frac = x - x0;
        i0[p] = (int)fminf(fmaxf(x0, 0.0f), (float)(W - 1));
        w0[p] = valid ? (1.0f - frac) : 0.0f;
        w1[p] = valid ? frac : 0.0f;
    }

    #pragma unroll
    for (int cc = 0; cc < CPW; ++cc) {
        // staged regs -> wave-private LDS (ds_write_b128, linear, conflict-free)
        *(f32x4*)(rb + 4 * lane)       = pre0[cc & 1];
        *(f32x4*)(rb + 256 + 4 * lane) = pre1[cc & 1];
        // refill the ring slot just consumed (keeps 4 dwordx4 in flight)
        if (cc + 2 < CPW) {
            const float* s2 = src + (size_t)(cc + 2) * chan_stride;
            pre0[cc & 1] = *(const f32x4*)(s2 + 4 * lane);
            pre1[cc & 1] = *(const f32x4*)(s2 + 256 + 4 * lane);
        }
        // adjacent-pair taps (ds_read2_b32), lerp, coalesced scalar NT stores
        float* d = dst + (size_t)cc * chan_stride;
        #pragma unroll
        for (int p = 0; p < 8; ++p) {
            int a = i0[p];
            float g0 = rb[a];
            float g1 = rb[a + 1];
            __builtin_nontemporal_store(w0[p] * g0 + w1[p] * g1, d + lane + 64 * p);
        }
    }
}

extern "C" void kernel_launch(void* const* d_in, const int* in_sizes, int n_in,
                              void* d_out, int out_size, void* d_ws, size_t ws_size,
                              hipStream_t stream) {
    const float* in1 = (const float*)d_in[0];
    const float* in2 = (const float*)d_in[1];
    float* out = (float*)d_out;

    dim3 grid(B * H, C / (WAVES * CPW)), block(WAVES * 64);
    resample1d_kernel<<<grid, block, 0, stream>>>(in1, in2, out);
}